// Round 6
// baseline (109.810 us; speedup 1.0000x reference)
//
#include <hip/hip_runtime.h>

// MSEBPRLoss, round 6: R5 structure, but pair_kernel j-data goes back through LDS.
// R5 post-mortem: global wave-uniform float4 loads serialized at ~300cyc each with
// VGPR=32 -> VALUBusy 15%, 50us. R2 proved LDS-broadcast reads run 80% busy.
//   enqueue 1: memset {ctrs, hist[4096]}
//   enqueue 2: prep (64 blocks): ticket=atomicAdd -> grid barrier -> redundant scan
//              -> pos=base+ticket -> EI/EJ + MSE partial
//   enqueue 3: pair (2080 tri tiles): stage EJ chunk in LDS, 8fma+7mul+1log / 8 pairs,
//              partials to ws, last-arriving block reduces 2144 partials, stores out.

#define N_ELEM 16384
#define NBUCK  4096
#define CHUNK  256
#define NCHUNK 64
#define NTILES 2080                 // NCHUNK*(NCHUNK+1)/2
#define NPREPB 64
#define NPARTS (NTILES + NPREPB)    // 2144 partials

__device__ __forceinline__ float fexp2(float x){ return __builtin_amdgcn_exp2f(x); }
__device__ __forceinline__ float flog2(float x){ return __builtin_amdgcn_logf(x); }

__device__ __forceinline__ int bucket_of(float t){
    int b = (int)(t * (float)NBUCK);      // monotone non-decreasing in t
    b = b < 0 ? 0 : b;
    return b > NBUCK - 1 ? NBUCK - 1 : b;
}

// ---- prep: hist-ticket + grid barrier + redundant scan + scatter + MSE ----
__global__ __launch_bounds__(256) void prep_kernel(
    const float* __restrict__ input, const float* __restrict__ target,
    int* __restrict__ ctrs, int* __restrict__ hist,
    float* __restrict__ EJ, float* __restrict__ EI, float* __restrict__ parts)
{
    const float L2E = 1.4426950408889634f;
    __shared__ int baseLds[NBUCK];        // 16 KB
    __shared__ int wtot[4];
    const int tid  = threadIdx.x;
    const int lane = tid & 63, wave = tid >> 6;
    const int gid  = blockIdx.x * 256 + tid;

    const float t = target[gid];          // coalesced
    const float x = input[gid];
    const int   b = bucket_of(t);
    const int ticket = atomicAdd(&hist[b], 1);   // device-scope; in-bucket rank

    // grid barrier (ctr pre-zeroed by memset; 64 blocks co-resident on 256 CUs)
    __syncthreads();
    if (tid == 0) {
        __hip_atomic_fetch_add(&ctrs[0], 1, __ATOMIC_ACQ_REL, __HIP_MEMORY_SCOPE_AGENT);
        while (__hip_atomic_load(&ctrs[0], __ATOMIC_ACQUIRE, __HIP_MEMORY_SCOPE_AGENT) < NPREPB)
            __builtin_amdgcn_s_sleep(4);
    }
    __syncthreads();

    // redundant exclusive scan of hist (4096) into LDS
    int v[16], le[16]; int s = 0;
    #pragma unroll
    for (int q = 0; q < 16; ++q)
        v[q] = __hip_atomic_load(&hist[16 * tid + q], __ATOMIC_RELAXED,
                                 __HIP_MEMORY_SCOPE_AGENT);
    #pragma unroll
    for (int q = 0; q < 16; ++q) { le[q] = s; s += v[q]; }
    int inc = s;
    #pragma unroll
    for (int d = 1; d < 64; d <<= 1) { int n = __shfl_up(inc, d, 64); if (lane >= d) inc += n; }
    if (lane == 63) wtot[wave] = inc;
    __syncthreads();
    int woff = 0;
    #pragma unroll
    for (int w = 0; w < 4; ++w) woff += (w < wave) ? wtot[w] : 0;
    const int texcl = woff + (inc - s);
    #pragma unroll
    for (int q = 0; q < 16; ++q) baseLds[16 * tid + q] = texcl + le[q];
    __syncthreads();

    // scatter + fused MSE:  (2/N^2)*0.5*d^2*count_i = d^2*count_i/N^2
    const int pos = baseLds[b] + ticket;
    EJ[pos] = fexp2(-x * L2E);
    EI[pos] = fexp2( x * L2E);
    const float d = x - t;
    float m = d * d * (float)(N_ELEM - 1 - pos) * (1.0f / (16384.0f * 16384.0f));

    #pragma unroll
    for (int off = 32; off; off >>= 1) m += __shfl_down(m, off, 64);
    __shared__ float ws[4];
    if (lane == 0) ws[wave] = m;
    __syncthreads();
    if (tid == 0)
        parts[NTILES + blockIdx.x] = (ws[0] + ws[1]) + (ws[2] + ws[3]);
}

// ---- pair: upper-triangle BPR; j-data via LDS broadcast; last block reduces ----
__global__ __launch_bounds__(256) void pair_kernel(
    const float* __restrict__ EI, const float* __restrict__ EJ,
    int* __restrict__ ctrs, float* __restrict__ parts, float* __restrict__ out)
{
    // triangular decode: tile (ci <= cj), u = cj(cj+1)/2 + ci
    const int u = blockIdx.x;
    int cj = (int)((sqrtf(8.0f * (float)u + 1.0f) - 1.0f) * 0.5f);
    while ((cj + 1) * (cj + 2) / 2 <= u) ++cj;
    while (cj * (cj + 1) / 2 > u) --cj;
    const int ci = u - cj * (cj + 1) / 2;

    const int tid = threadIdx.x, lane = tid & 63;
    const int wu = __builtin_amdgcn_readfirstlane((int)(threadIdx.x >> 6));

    // stage this tile's 256 j-values into LDS (coalesced 1KB load)
    __shared__ __align__(16) float ejLds[CHUNK];
    ejLds[tid] = EJ[cj * CHUNK + tid];

    // 4 i's per lane; coalesced loads
    float Eir[4];
    #pragma unroll
    for (int k = 0; k < 4; ++k) Eir[k] = EI[ci * CHUNK + 64 * k + lane];
    __syncthreads();

    const float* __restrict__ ejp = &ejLds[wu * 64];   // wave-uniform LDS base
    float la[4] = {0.f, 0.f, 0.f, 0.f};

    if (ci != cj) {
        // every pair valid: 8 fma + 7 mul + 1 v_log per 8 pairs per lane
        #pragma unroll
        for (int jj = 0; jj < 64; jj += 8) {
            const float4 eA = *(const float4*)(ejp + jj);      // ds_read_b128 broadcast
            const float4 eB = *(const float4*)(ejp + jj + 4);
            #pragma unroll
            for (int k = 0; k < 4; ++k) {
                const float E = Eir[k];
                float p = fmaf(E, eA.x, 1.0f);   // product of 8 factors <= ~2^104: safe
                p *= fmaf(E, eA.y, 1.0f);
                p *= fmaf(E, eA.z, 1.0f);
                p *= fmaf(E, eA.w, 1.0f);
                p *= fmaf(E, eB.x, 1.0f);
                p *= fmaf(E, eB.y, 1.0f);
                p *= fmaf(E, eB.z, 1.0f);
                p *= fmaf(E, eB.w, 1.0f);
                la[k] += flog2(p);
            }
        }
    } else {
        // diagonal tile: include iff j_local > i_local
        #pragma unroll
        for (int jj = 0; jj < 64; jj += 8) {
            const float4 eA = *(const float4*)(ejp + jj);
            const float4 eB = *(const float4*)(ejp + jj + 4);
            const int jb = wu * 64 + jj;
            #pragma unroll
            for (int k = 0; k < 4; ++k) {
                const float E = Eir[k];
                const int thr = 64 * k + lane;
                float p = 1.0f;
                p *= (jb + 0 > thr) ? fmaf(E, eA.x, 1.0f) : 1.0f;
                p *= (jb + 1 > thr) ? fmaf(E, eA.y, 1.0f) : 1.0f;
                p *= (jb + 2 > thr) ? fmaf(E, eA.z, 1.0f) : 1.0f;
                p *= (jb + 3 > thr) ? fmaf(E, eA.w, 1.0f) : 1.0f;
                p *= (jb + 4 > thr) ? fmaf(E, eB.x, 1.0f) : 1.0f;
                p *= (jb + 5 > thr) ? fmaf(E, eB.y, 1.0f) : 1.0f;
                p *= (jb + 6 > thr) ? fmaf(E, eB.z, 1.0f) : 1.0f;
                p *= (jb + 7 > thr) ? fmaf(E, eB.w, 1.0f) : 1.0f;
                la[k] += flog2(p);
            }
        }
    }

    float v = (la[0] + la[1]) + (la[2] + la[3]);
    #pragma unroll
    for (int off = 32; off; off >>= 1) v += __shfl_down(v, off, 64);
    __shared__ float ws[4];
    __shared__ int last;
    if (lane == 0) ws[tid >> 6] = v;
    __syncthreads();
    if (tid == 0) {
        // (2/N^2)*0.5*ln2*sum(log2) = (ln2/N^2)*sum(log2)
        const float part = ((ws[0] + ws[1]) + (ws[2] + ws[3])) *
                           (0.6931471805599453f / (16384.0f * 16384.0f));
        __hip_atomic_store(&parts[u], part, __ATOMIC_RELAXED, __HIP_MEMORY_SCOPE_AGENT);
        const int old = __hip_atomic_fetch_add(&ctrs[1], 1, __ATOMIC_ACQ_REL,
                                               __HIP_MEMORY_SCOPE_AGENT);
        last = (old == NTILES - 1);
    }
    __syncthreads();
    if (last) {
        float a = 0.f;
        for (int i = tid; i < NPARTS; i += 256)
            a += __hip_atomic_load(&parts[i], __ATOMIC_RELAXED, __HIP_MEMORY_SCOPE_AGENT);
        #pragma unroll
        for (int off = 32; off; off >>= 1) a += __shfl_down(a, off, 64);
        __syncthreads();
        if (lane == 0) ws[tid >> 6] = a;
        __syncthreads();
        if (tid == 0)
            out[0] = (ws[0] + ws[1]) + (ws[2] + ws[3]);
    }
}

extern "C" void kernel_launch(void* const* d_in, const int* in_sizes, int n_in,
                              void* d_out, int out_size, void* d_ws, size_t ws_size,
                              hipStream_t stream) {
    const float* input  = (const float*)d_in[0];
    const float* target = (const float*)d_in[1];
    float* out  = (float*)d_out;
    int*   ctrs = (int*)d_ws;                 // [0]=prep barrier, [1]=pair done-count
    int*   hist = ctrs + 8;                   // 4096 ints
    float* EJ   = (float*)(hist + NBUCK);     // 16384 floats
    float* EI   = EJ + N_ELEM;                // 16384 floats
    float* parts = EI + N_ELEM;               // 2144 floats

    hipMemsetAsync(ctrs, 0, (8 + NBUCK) * sizeof(int), stream);
    prep_kernel<<<NPREPB, 256, 0, stream>>>(input, target, ctrs, hist, EJ, EI, parts);
    pair_kernel<<<NTILES, 256, 0, stream>>>(EI, EJ, ctrs, parts, out);
}

// Round 7
// 87.143 us; speedup vs baseline: 1.2601x; 1.2601x over previous
//
#include <hip/hip_runtime.h>

// MSEBPRLoss, round 7.
// R6 post-mortem: pair kernel was bound by 2080 serialized same-address device
// atomics (~53 cyc each ~= 46us), NOT load latency. Also R4(6 nodes)=97.8 vs
// R5(3 nodes)=108.2 -> dispatch gaps ~1us; split prep (R4) beats fused-barrier prep.
// Fix: 260 pair blocks x 8 tiles (incremental triangular decode, EJ restaged only
// on cj change), done-counter split into 4 cache-line-separated sub-counters
// (260=4x65) + master; last-master block reduces 324 partials and stores out.
//   enqueues: memset{ctrs,hist} -> hist -> scan -> scatter(+MSE parts) -> pair.

#define N_ELEM 16384
#define NBUCK  4096
#define CHUNK  256
#define NCHUNK 64
#define NTILES 2080                 // NCHUNK*(NCHUNK+1)/2
#define PAIRB  260                  // pair blocks
#define TPB    8                    // tiles per pair block (260*8 = 2080)
#define NSUB   4                    // sub-counters, 260 = 4*65
#define SUBQ   65
#define NPARTS (PAIRB + NCHUNK)     // 324 partials

__device__ __forceinline__ float fexp2(float x){ return __builtin_amdgcn_exp2f(x); }
__device__ __forceinline__ float flog2(float x){ return __builtin_amdgcn_logf(x); }

__device__ __forceinline__ int bucket_of(float t){
    int b = (int)(t * (float)NBUCK);      // monotone non-decreasing in t
    b = b < 0 ? 0 : b;
    return b > NBUCK - 1 ? NBUCK - 1 : b;
}

// ---- K1: global histogram (64 blocks) ----
__global__ __launch_bounds__(256) void hist_kernel(
    const float* __restrict__ target, int* __restrict__ hist)
{
    const int gid = blockIdx.x * 256 + threadIdx.x;
    atomicAdd(&hist[bucket_of(target[gid])], 1);
}

// ---- K2: exclusive scan of 4096 ints, 1 block x 256, 16/thread ----
__global__ __launch_bounds__(256) void scan_kernel(
    const int* __restrict__ hist, int* __restrict__ base)
{
    const int tid = threadIdx.x, lane = tid & 63, wave = tid >> 6;
    int v[16];
    const int4* hp = (const int4*)(hist + 16 * tid);
    #pragma unroll
    for (int q = 0; q < 4; ++q) {
        const int4 h = hp[q];
        v[4*q+0] = h.x; v[4*q+1] = h.y; v[4*q+2] = h.z; v[4*q+3] = h.w;
    }
    int le[16]; int s = 0;
    #pragma unroll
    for (int q = 0; q < 16; ++q) { le[q] = s; s += v[q]; }
    int inc = s;
    #pragma unroll
    for (int d = 1; d < 64; d <<= 1) { int n = __shfl_up(inc, d, 64); if (lane >= d) inc += n; }
    __shared__ int wtot[4];
    if (lane == 63) wtot[wave] = inc;
    __syncthreads();
    int woff = 0;
    #pragma unroll
    for (int w = 0; w < 4; ++w) woff += (w < wave) ? wtot[w] : 0;
    const int texcl = woff + (inc - s);
    int4* bp = (int4*)(base + 16 * tid);
    #pragma unroll
    for (int q = 0; q < 4; ++q) {
        int4 o;
        o.x = texcl + le[4*q+0]; o.y = texcl + le[4*q+1];
        o.z = texcl + le[4*q+2]; o.w = texcl + le[4*q+3];
        bp[q] = o;
    }
}

// ---- K3: scatter into sorted order + MSE partial per block ----
__global__ __launch_bounds__(256) void scatter_kernel(
    const float* __restrict__ input, const float* __restrict__ target,
    int* __restrict__ base, float* __restrict__ EJ, float* __restrict__ EI,
    float* __restrict__ parts)
{
    const float L2E = 1.4426950408889634f;
    const int tid = threadIdx.x;
    const int gid = blockIdx.x * 256 + tid;
    const float t = target[gid];
    const float x = input[gid];
    const int pos = atomicAdd(&base[bucket_of(t)], 1);
    EJ[pos] = fexp2(-x * L2E);
    EI[pos] = fexp2( x * L2E);
    const float d = x - t;
    // (2/N^2)*0.5*d^2*count_i = d^2*count_i/N^2
    float m = d * d * (float)(N_ELEM - 1 - pos) * (1.0f / (16384.0f * 16384.0f));

    #pragma unroll
    for (int off = 32; off; off >>= 1) m += __shfl_down(m, off, 64);
    __shared__ float ws[4];
    if ((tid & 63) == 0) ws[tid >> 6] = m;
    __syncthreads();
    if (tid == 0)
        parts[PAIRB + blockIdx.x] = (ws[0] + ws[1]) + (ws[2] + ws[3]);
}

// ---- K4: upper-triangle BPR, 8 tiles/block, hierarchical done-counters ----
__global__ __launch_bounds__(256) void pair_kernel(
    const float* __restrict__ EI, const float* __restrict__ EJ,
    int* __restrict__ ctrs, float* __restrict__ parts, float* __restrict__ out)
{
    const int b   = blockIdx.x;
    const int tid = threadIdx.x, lane = tid & 63;
    const int wu  = __builtin_amdgcn_readfirstlane((int)(threadIdx.x >> 6));

    // decode first tile of this block's range [8b, 8b+8): u = cj(cj+1)/2 + ci
    const int u0 = b * TPB;
    int cj = (int)((sqrtf(8.0f * (float)u0 + 1.0f) - 1.0f) * 0.5f);
    while ((cj + 1) * (cj + 2) / 2 <= u0) ++cj;
    while (cj * (cj + 1) / 2 > u0) --cj;
    int ci = u0 - cj * (cj + 1) / 2;

    __shared__ __align__(16) float ejLds[CHUNK];
    float la[4] = {0.f, 0.f, 0.f, 0.f};
    int cjCur = -1;

    for (int t = 0; t < TPB; ++t) {
        if (cj != cjCur) {                         // block-uniform branch
            __syncthreads();                       // prior tile's reads done
            ejLds[tid] = EJ[cj * CHUNK + tid];     // coalesced 1KB stage
            cjCur = cj;
            __syncthreads();
        }
        float Eir[4];
        #pragma unroll
        for (int k = 0; k < 4; ++k) Eir[k] = EI[ci * CHUNK + 64 * k + lane];
        const float* __restrict__ ejp = &ejLds[wu * 64];

        if (ci != cj) {
            // every pair valid: 8 fma + 7 mul + 1 v_log per 8 pairs per lane
            #pragma unroll
            for (int jj = 0; jj < 64; jj += 8) {
                const float4 eA = *(const float4*)(ejp + jj);
                const float4 eB = *(const float4*)(ejp + jj + 4);
                #pragma unroll
                for (int k = 0; k < 4; ++k) {
                    const float E = Eir[k];
                    float p = fmaf(E, eA.x, 1.0f);   // product of 8 <= ~2^104: safe
                    p *= fmaf(E, eA.y, 1.0f);
                    p *= fmaf(E, eA.z, 1.0f);
                    p *= fmaf(E, eA.w, 1.0f);
                    p *= fmaf(E, eB.x, 1.0f);
                    p *= fmaf(E, eB.y, 1.0f);
                    p *= fmaf(E, eB.z, 1.0f);
                    p *= fmaf(E, eB.w, 1.0f);
                    la[k] += flog2(p);
                }
            }
        } else {
            // diagonal tile: include iff j_local > i_local
            #pragma unroll
            for (int jj = 0; jj < 64; jj += 8) {
                const float4 eA = *(const float4*)(ejp + jj);
                const float4 eB = *(const float4*)(ejp + jj + 4);
                const int jb = wu * 64 + jj;
                #pragma unroll
                for (int k = 0; k < 4; ++k) {
                    const float E = Eir[k];
                    const int thr = 64 * k + lane;
                    float p = 1.0f;
                    p *= (jb + 0 > thr) ? fmaf(E, eA.x, 1.0f) : 1.0f;
                    p *= (jb + 1 > thr) ? fmaf(E, eA.y, 1.0f) : 1.0f;
                    p *= (jb + 2 > thr) ? fmaf(E, eA.z, 1.0f) : 1.0f;
                    p *= (jb + 3 > thr) ? fmaf(E, eA.w, 1.0f) : 1.0f;
                    p *= (jb + 4 > thr) ? fmaf(E, eB.x, 1.0f) : 1.0f;
                    p *= (jb + 5 > thr) ? fmaf(E, eB.y, 1.0f) : 1.0f;
                    p *= (jb + 6 > thr) ? fmaf(E, eB.z, 1.0f) : 1.0f;
                    p *= (jb + 7 > thr) ? fmaf(E, eB.w, 1.0f) : 1.0f;
                    la[k] += flog2(p);
                }
            }
        }
        // next tile: ci ascends within row cj, then next row
        if (ci == cj) { ++cj; ci = 0; } else { ++ci; }
    }

    float v = (la[0] + la[1]) + (la[2] + la[3]);
    #pragma unroll
    for (int off = 32; off; off >>= 1) v += __shfl_down(v, off, 64);
    __shared__ float ws[4];
    __shared__ int lastFlag;
    if (lane == 0) ws[wu] = v;
    __syncthreads();
    if (tid == 0) {
        // (2/N^2)*0.5*ln2*sum(log2) = (ln2/N^2)*sum(log2)
        const float part = ((ws[0] + ws[1]) + (ws[2] + ws[3])) *
                           (0.6931471805599453f / (16384.0f * 16384.0f));
        __hip_atomic_store(&parts[b], part, __ATOMIC_RELAXED, __HIP_MEMORY_SCOPE_AGENT);
        // hierarchical completion: 4 sub-counters on separate 128B lines -> master
        const int sub = b & (NSUB - 1);
        const int old = __hip_atomic_fetch_add(&ctrs[32 * sub], 1, __ATOMIC_ACQ_REL,
                                               __HIP_MEMORY_SCOPE_AGENT);
        int lf = 0;
        if (old == SUBQ - 1) {
            const int om = __hip_atomic_fetch_add(&ctrs[128], 1, __ATOMIC_ACQ_REL,
                                                  __HIP_MEMORY_SCOPE_AGENT);
            lf = (om == NSUB - 1);
        }
        lastFlag = lf;
    }
    __syncthreads();
    if (lastFlag) {
        // last block (transitively synced with all releases): sum 324 partials
        float a = 0.f;
        for (int i = tid; i < NPARTS; i += 256)
            a += __hip_atomic_load(&parts[i], __ATOMIC_RELAXED, __HIP_MEMORY_SCOPE_AGENT);
        #pragma unroll
        for (int off = 32; off; off >>= 1) a += __shfl_down(a, off, 64);
        __syncthreads();
        if (lane == 0) ws[wu] = a;
        __syncthreads();
        if (tid == 0)
            out[0] = (ws[0] + ws[1]) + (ws[2] + ws[3]);
    }
}

extern "C" void kernel_launch(void* const* d_in, const int* in_sizes, int n_in,
                              void* d_out, int out_size, void* d_ws, size_t ws_size,
                              hipStream_t stream) {
    const float* input  = (const float*)d_in[0];
    const float* target = (const float*)d_in[1];
    float* out  = (float*)d_out;
    int*   ctrs = (int*)d_ws;                  // [0,32,64,96]=sub, [128]=master
    int*   hist = ctrs + 160;                  // 4096 ints (16B-aligned: 640B offset)
    int*   base = hist + NBUCK;                // 4096 ints
    float* EJ   = (float*)(base + NBUCK);      // 16384 floats
    float* EI   = EJ + N_ELEM;                 // 16384 floats
    float* parts = EI + N_ELEM;                // 324 floats

    hipMemsetAsync(ctrs, 0, (160 + NBUCK) * sizeof(int), stream);  // ctrs + hist
    hist_kernel<<<NCHUNK, 256, 0, stream>>>(target, hist);
    scan_kernel<<<1, 256, 0, stream>>>(hist, base);
    scatter_kernel<<<NCHUNK, 256, 0, stream>>>(input, target, base, EJ, EI, parts);
    pair_kernel<<<PAIRB, 256, 0, stream>>>(EI, EJ, ctrs, parts, out);
}

// Round 8
// 81.019 us; speedup vs baseline: 1.3554x; 1.0756x over previous
//
#include <hip/hip_runtime.h>

// MSEBPRLoss, round 8.
// R7 post-mortem: pair still ~35-39us hidden under fill rows. All slow variants
// (R5-R7) used ACQ_REL agent-scope atomics for completion; R2's relaxed
// unsafeAtomicAdd ran 1024 adds fully hidden at 80% busy. Theory: agent-scope
// acq/rel cache maintenance per block-end atomic is the cost, not chain length.
// Fix: R2-style relaxed unsafeAtomicAdd(out) everywhere; out[0] zeroed by scan
// kernel (stream order guarantees it precedes scatter/pair atomics).
// Pair: 208 blocks x 1024 thr x 10 tiles -> <=1 block/CU (perfect balance),
// 13 waves/CU latency hiding, only 272 total relaxed atomics.
//   enqueues: memset{hist 16KB} -> hist(64) -> scan(1, zeroes out) ->
//             scatter(64, MSE->atomic) -> pair(208, BPR->atomic).

#define N_ELEM 16384
#define NBUCK  4096
#define CHUNK  256
#define NCHUNK 64
#define NTILES 2080                 // 64*65/2
#define PAIRB  208                  // pair blocks (208*10 = 2080)
#define TPB    10                   // tiles per pair block

__device__ __forceinline__ float fexp2(float x){ return __builtin_amdgcn_exp2f(x); }
__device__ __forceinline__ float flog2(float x){ return __builtin_amdgcn_logf(x); }

__device__ __forceinline__ int bucket_of(float t){
    int b = (int)(t * (float)NBUCK);      // monotone non-decreasing in t
    b = b < 0 ? 0 : b;
    return b > NBUCK - 1 ? NBUCK - 1 : b;
}

// ---- K1: global histogram (64 blocks) ----
__global__ __launch_bounds__(256) void hist_kernel(
    const float* __restrict__ target, int* __restrict__ hist)
{
    const int gid = blockIdx.x * 256 + threadIdx.x;
    atomicAdd(&hist[bucket_of(target[gid])], 1);
}

// ---- K2: exclusive scan of 4096 ints (1 block x 256, 16/thread); zeroes out ----
__global__ __launch_bounds__(256) void scan_kernel(
    const int* __restrict__ hist, int* __restrict__ base, float* __restrict__ out)
{
    const int tid = threadIdx.x, lane = tid & 63, wave = tid >> 6;
    if (tid == 0) out[0] = 0.0f;          // completes before scatter/pair dispatches
    int v[16];
    const int4* hp = (const int4*)(hist + 16 * tid);
    #pragma unroll
    for (int q = 0; q < 4; ++q) {
        const int4 h = hp[q];
        v[4*q+0] = h.x; v[4*q+1] = h.y; v[4*q+2] = h.z; v[4*q+3] = h.w;
    }
    int le[16]; int s = 0;
    #pragma unroll
    for (int q = 0; q < 16; ++q) { le[q] = s; s += v[q]; }
    int inc = s;
    #pragma unroll
    for (int d = 1; d < 64; d <<= 1) { int n = __shfl_up(inc, d, 64); if (lane >= d) inc += n; }
    __shared__ int wtot[4];
    if (lane == 63) wtot[wave] = inc;
    __syncthreads();
    int woff = 0;
    #pragma unroll
    for (int w = 0; w < 4; ++w) woff += (w < wave) ? wtot[w] : 0;
    const int texcl = woff + (inc - s);
    int4* bp = (int4*)(base + 16 * tid);
    #pragma unroll
    for (int q = 0; q < 4; ++q) {
        int4 o;
        o.x = texcl + le[4*q+0]; o.y = texcl + le[4*q+1];
        o.z = texcl + le[4*q+2]; o.w = texcl + le[4*q+3];
        bp[q] = o;
    }
}

// ---- K3: scatter into sorted order + MSE term -> relaxed atomic ----
__global__ __launch_bounds__(256) void scatter_kernel(
    const float* __restrict__ input, const float* __restrict__ target,
    int* __restrict__ base, float* __restrict__ EJ, float* __restrict__ EI,
    float* __restrict__ out)
{
    const float L2E = 1.4426950408889634f;
    const int tid = threadIdx.x;
    const int gid = blockIdx.x * 256 + tid;
    const float t = target[gid];
    const float x = input[gid];
    const int pos = atomicAdd(&base[bucket_of(t)], 1);
    EJ[pos] = fexp2(-x * L2E);
    EI[pos] = fexp2( x * L2E);
    const float d = x - t;
    // (2/N^2)*0.5*d^2*count_i = d^2*count_i/N^2
    float m = d * d * (float)(N_ELEM - 1 - pos) * (1.0f / (16384.0f * 16384.0f));

    #pragma unroll
    for (int off = 32; off; off >>= 1) m += __shfl_down(m, off, 64);
    __shared__ float ws[4];
    if ((tid & 63) == 0) ws[tid >> 6] = m;
    __syncthreads();
    if (tid == 0)
        unsafeAtomicAdd(out, (ws[0] + ws[1]) + (ws[2] + ws[3]));  // relaxed HW f32 add
}

// ---- K4: upper-triangle BPR; 1024 thr, 10 tiles/block, relaxed atomic out ----
__global__ __launch_bounds__(1024) void pair_kernel(
    const float* __restrict__ EI, const float* __restrict__ EJ,
    float* __restrict__ out)
{
    const int b   = blockIdx.x;
    const int tid = threadIdx.x, lane = tid & 63;
    const int wu  = __builtin_amdgcn_readfirstlane((int)(threadIdx.x >> 6)); // 0..15

    // decode first tile of range [10b, 10b+10): u = cj(cj+1)/2 + ci
    const int u0 = b * TPB;
    int cj = (int)((sqrtf(8.0f * (float)u0 + 1.0f) - 1.0f) * 0.5f);
    while ((cj + 1) * (cj + 2) / 2 <= u0) ++cj;
    while (cj * (cj + 1) / 2 > u0) --cj;
    int ci = u0 - cj * (cj + 1) / 2;

    __shared__ __align__(16) float ejLds[CHUNK];
    float la[4] = {0.f, 0.f, 0.f, 0.f};
    int cjCur = -1;

    for (int t = 0; t < TPB; ++t) {
        if (cj != cjCur) {                         // block-uniform branch
            __syncthreads();
            if (tid < CHUNK) ejLds[tid] = EJ[cj * CHUNK + tid];
            cjCur = cj;
            __syncthreads();
        }
        float Eir[4];
        #pragma unroll
        for (int k = 0; k < 4; ++k) Eir[k] = EI[ci * CHUNK + 64 * k + lane];
        // wave w covers j in [16w, 16w+16) of this tile
        const float* __restrict__ ejp = &ejLds[wu * 16];

        if (ci != cj) {
            // every pair valid: 8 fma + 7 mul + 1 v_log per 8 pairs per lane
            #pragma unroll
            for (int jj = 0; jj < 16; jj += 8) {
                const float4 eA = *(const float4*)(ejp + jj);      // ds_read_b128
                const float4 eB = *(const float4*)(ejp + jj + 4);  // broadcast, no conflict
                #pragma unroll
                for (int k = 0; k < 4; ++k) {
                    const float E = Eir[k];
                    float p = fmaf(E, eA.x, 1.0f);   // product of 8 <= ~2^104: safe
                    p *= fmaf(E, eA.y, 1.0f);
                    p *= fmaf(E, eA.z, 1.0f);
                    p *= fmaf(E, eA.w, 1.0f);
                    p *= fmaf(E, eB.x, 1.0f);
                    p *= fmaf(E, eB.y, 1.0f);
                    p *= fmaf(E, eB.z, 1.0f);
                    p *= fmaf(E, eB.w, 1.0f);
                    la[k] += flog2(p);
                }
            }
        } else {
            // diagonal tile: include iff j_local > i_local
            #pragma unroll
            for (int jj = 0; jj < 16; jj += 8) {
                const float4 eA = *(const float4*)(ejp + jj);
                const float4 eB = *(const float4*)(ejp + jj + 4);
                const int jb = wu * 16 + jj;
                #pragma unroll
                for (int k = 0; k < 4; ++k) {
                    const float E = Eir[k];
                    const int thr = 64 * k + lane;
                    float p = 1.0f;
                    p *= (jb + 0 > thr) ? fmaf(E, eA.x, 1.0f) : 1.0f;
                    p *= (jb + 1 > thr) ? fmaf(E, eA.y, 1.0f) : 1.0f;
                    p *= (jb + 2 > thr) ? fmaf(E, eA.z, 1.0f) : 1.0f;
                    p *= (jb + 3 > thr) ? fmaf(E, eA.w, 1.0f) : 1.0f;
                    p *= (jb + 4 > thr) ? fmaf(E, eB.x, 1.0f) : 1.0f;
                    p *= (jb + 5 > thr) ? fmaf(E, eB.y, 1.0f) : 1.0f;
                    p *= (jb + 6 > thr) ? fmaf(E, eB.z, 1.0f) : 1.0f;
                    p *= (jb + 7 > thr) ? fmaf(E, eB.w, 1.0f) : 1.0f;
                    la[k] += flog2(p);
                }
            }
        }
        // next tile: ci ascends within row cj, then next row
        if (ci == cj) { ++cj; ci = 0; } else { ++ci; }
    }

    float v = (la[0] + la[1]) + (la[2] + la[3]);
    #pragma unroll
    for (int off = 32; off; off >>= 1) v += __shfl_down(v, off, 64);
    __shared__ float ws[16];
    if (lane == 0) ws[wu] = v;
    __syncthreads();
    if (tid == 0) {
        float s = 0.f;
        #pragma unroll
        for (int w = 0; w < 16; ++w) s += ws[w];
        // (2/N^2)*0.5*ln2*sum(log2) = (ln2/N^2)*sum(log2)
        unsafeAtomicAdd(out, s * (0.6931471805599453f / (16384.0f * 16384.0f)));
    }
}

extern "C" void kernel_launch(void* const* d_in, const int* in_sizes, int n_in,
                              void* d_out, int out_size, void* d_ws, size_t ws_size,
                              hipStream_t stream) {
    const float* input  = (const float*)d_in[0];
    const float* target = (const float*)d_in[1];
    float* out  = (float*)d_out;
    int*   hist = (int*)d_ws;                  // 4096 ints
    int*   base = hist + NBUCK;                // 4096 ints
    float* EJ   = (float*)(base + NBUCK);      // 16384 floats
    float* EI   = EJ + N_ELEM;                 // 16384 floats

    hipMemsetAsync(hist, 0, NBUCK * sizeof(int), stream);
    hist_kernel<<<NCHUNK, 256, 0, stream>>>(target, hist);
    scan_kernel<<<1, 256, 0, stream>>>(hist, base, out);
    scatter_kernel<<<NCHUNK, 256, 0, stream>>>(input, target, base, EJ, EI, out);
    pair_kernel<<<PAIRB, 1024, 0, stream>>>(EI, EJ, out);
}